// Round 2
// baseline (398.419 us; speedup 1.0000x reference)
//
#include <hip/hip_runtime.h>

#define N_NODES 2048
#define F_IN    2048
#define G1      10
#define NCLS    10
#define NEDGE   65536
#define JC      32          // split-K chunks
#define JPER    64          // K elems per chunk
#define ROWS    128         // rows per block tile
#define ZS      64          // scatter slices per k-half
#define GRID    512         // 2 blocks/CU x 256 CU -> all co-resident (LDS allows 4/CU)
#define BLK     256

// Device-global intermediates — fully overwritten every call (no stale state).
__device__ float g_p[JC * 20 * N_NODES];          // split-K partials (5.25 MB)
__device__ int   g_deg[N_NODES];                  // degree (zeroed in P1, atomics in P2)
__device__ float g_y[N_NODES * 20];               // [row][k]: k<10 x@W0, k>=10 x@W1
__device__ float g_zp[2 * ZS * N_NODES * 5];      // scatter partials (5.25 MB)
__device__ float g_z[N_NODES * G1];               // reduced Tx1@W1 scatter

// Software grid barrier state (sense via monotonically increasing generation).
// bss zero-init at module load; barrier leaves {count=0, gen+=1} -> reusable
// across graph replays.
__device__ unsigned g_bar_count = 0;
__device__ unsigned g_bar_gen   = 0;

__device__ __forceinline__ void grid_barrier() {
    __syncthreads();
    if (threadIdx.x == 0) {
        __threadfence();  // device-scope: flush our writes for cross-XCD readers
        unsigned gen = __hip_atomic_load(&g_bar_gen, __ATOMIC_ACQUIRE,
                                         __HIP_MEMORY_SCOPE_AGENT);
        unsigned prev = __hip_atomic_fetch_add(&g_bar_count, 1u, __ATOMIC_ACQ_REL,
                                               __HIP_MEMORY_SCOPE_AGENT);
        if (prev == (unsigned)(gridDim.x - 1)) {
            __hip_atomic_store(&g_bar_count, 0u, __ATOMIC_RELAXED,
                               __HIP_MEMORY_SCOPE_AGENT);
            __hip_atomic_fetch_add(&g_bar_gen, 1u, __ATOMIC_RELEASE,
                                   __HIP_MEMORY_SCOPE_AGENT);
        } else {
            while (__hip_atomic_load(&g_bar_gen, __ATOMIC_ACQUIRE,
                                     __HIP_MEMORY_SCOPE_AGENT) == gen)
                __builtin_amdgcn_s_sleep(2);
        }
    }
    __syncthreads();
}

__global__ __launch_bounds__(256, 2) void k_fused(const float* __restrict__ x,
                                                  const int* __restrict__ ei,
                                                  const float* __restrict__ W0,
                                                  const float* __restrict__ W1,
                                                  const float* __restrict__ b,
                                                  const float* __restrict__ Wf,
                                                  const float* __restrict__ bfv,
                                                  float* __restrict__ out) {
    __shared__ __align__(16) float smem[N_NODES * 5];   // 40 KB
    const int tid = threadIdx.x;
    const int bx  = blockIdx.x;

    // ---- Phase 1: split-K GEMM x@[W0|W1] -> g_p; block 0 zeroes g_deg ----
    {
        int jc   = bx & (JC - 1);          // 0..31
        int rb   = bx >> 5;                // 0..15
        int j0   = jc * JPER;
        int row0 = rb * ROWS;
        // stage 128x64 x-tile, LDS stride 65 (bank-conflict-free both sides)
        #pragma unroll
        for (int rep = 0; rep < 8; ++rep) {
            int idx = rep * 256 + tid;
            int r = idx >> 4, c4 = idx & 15;
            float4 v = *(const float4*)(x + (size_t)(row0 + r) * F_IN + j0 + c4 * 4);
            float* d = smem + r * 65 + c4 * 4;
            d[0] = v.x; d[1] = v.y; d[2] = v.z; d[3] = v.w;
        }
        if (bx == 0) {
            #pragma unroll
            for (int t = tid; t < N_NODES; t += 256) g_deg[t] = 0;
        }
        __syncthreads();

        int ri = tid & (ROWS - 1);         // row within tile
        int kg = tid >> 7;                 // wave-uniform: 0 -> W0, 1 -> W1
        const float* Wm = kg ? W1 : W0;
        float acc[G1];
        #pragma unroll
        for (int k = 0; k < G1; ++k) acc[k] = 0.f;
        const float* xr = smem + ri * 65;
        #pragma unroll
        for (int j = 0; j < JPER; ++j) {
            float xu = xr[j];
            const float* wr = Wm + (size_t)(j0 + j) * G1;   // uniform -> s_load
            #pragma unroll
            for (int k = 0; k < G1; ++k) acc[k] += xu * wr[k];
        }
        int row = row0 + ri;
        #pragma unroll
        for (int k = 0; k < G1; ++k)
            g_p[((size_t)jc * 20 + kg * 10 + k) * N_NODES + row] = acc[k];  // coalesced
    }
    grid_barrier();

    // ---- Phase 2: reduce partials -> g_y ; degree histogram via global atomics ----
    {
        int t = bx * 256 + tid;            // 0..131071
        if (t < N_NODES * 20) {
            int k = t >> 11, row = t & (N_NODES - 1);
            float s = 0.f;
            #pragma unroll
            for (int jc = 0; jc < JC; ++jc)
                s += g_p[((size_t)jc * 20 + k) * N_NODES + row];
            g_y[row * 20 + k] = s;
        } else if (t < N_NODES * 20 + NEDGE) {
            atomicAdd(&g_deg[ei[t - N_NODES * 20]], 1);   // row part of edge_index
        }
    }
    grid_barrier();

    // ---- Phase 3: LDS-privatized edge scatter in projected space ----
    if (bx < 2 * ZS) {
        int khalf = bx >> 6;
        int slice = bx & (ZS - 1);
        float4* zl4 = (float4*)smem;
        #pragma unroll
        for (int t = tid; t < N_NODES * 5 / 4; t += 256)
            zl4[t] = make_float4(0.f, 0.f, 0.f, 0.f);
        __syncthreads();
        int base = slice * (NEDGE / ZS);   // 1024 edges per slice
        #pragma unroll
        for (int u = 0; u < NEDGE / ZS / 256; ++u) {
            int e = base + u * 256 + tid;
            int r = ei[e], c = ei[NEDGE + e];
            int dr = g_deg[r], dc = g_deg[c];
            float w = -(dr > 0 ? rsqrtf((float)dr) : 0.f) *
                       (dc > 0 ? rsqrtf((float)dc) : 0.f);
            const float* y1 = g_y + r * 20 + 10 + khalf * 5;
            float* zz = smem + c * 5;
            #pragma unroll
            for (int kk = 0; kk < 5; ++kk) atomicAdd(&zz[kk], w * y1[kk]);
        }
        __syncthreads();
        float4* dst = (float4*)(g_zp + ((size_t)khalf * ZS + slice) * (N_NODES * 5));
        #pragma unroll
        for (int t = tid; t < N_NODES * 5 / 4; t += 256) dst[t] = zl4[t];
    }
    grid_barrier();

    // ---- Phase 4a: reduce scatter partials -> g_z ----
    {
        int t = bx * 256 + tid;
        if (t < N_NODES * G1) {
            int khalf = t / (N_NODES * 5);
            int rem   = t % (N_NODES * 5);
            float s = 0.f;
            #pragma unroll
            for (int sl = 0; sl < ZS; ++sl)
                s += g_zp[((size_t)khalf * ZS + sl) * (N_NODES * 5) + rem];
            int i = rem / 5, kk = rem - i * 5;
            g_z[i * 10 + khalf * 5 + kk] = s;
        }
    }
    grid_barrier();

    // ---- Phase 4b: epilogue relu(y0+z+b) @ Wf + log_softmax ----
    {
        int i = bx * 256 + tid;
        if (i < N_NODES) {
            float h[G1];
            #pragma unroll
            for (int k = 0; k < G1; ++k)
                h[k] = fmaxf(g_y[i * 20 + k] + g_z[i * 10 + k] + b[k], 0.f);
            float lo[NCLS];
            #pragma unroll
            for (int c = 0; c < NCLS; ++c) lo[c] = bfv[c];
            #pragma unroll
            for (int k = 0; k < G1; ++k) {
                float hk = h[k];
                #pragma unroll
                for (int c = 0; c < NCLS; ++c) lo[c] += hk * Wf[k * NCLS + c];
            }
            float m = lo[0];
            #pragma unroll
            for (int c = 1; c < NCLS; ++c) m = fmaxf(m, lo[c]);
            float s = 0.f;
            #pragma unroll
            for (int c = 0; c < NCLS; ++c) s += expf(lo[c] - m);
            float ls = logf(s);
            #pragma unroll
            for (int c = 0; c < NCLS; ++c) out[i * NCLS + c] = lo[c] - m - ls;
        }
    }
}

extern "C" void kernel_launch(void* const* d_in, const int* in_sizes, int n_in,
                              void* d_out, int out_size, void* d_ws, size_t ws_size,
                              hipStream_t stream) {
    const float* x   = (const float*)d_in[0];
    const int*   ei  = (const int*)d_in[1];
    const float* W0  = (const float*)d_in[2];
    const float* W1  = (const float*)d_in[3];
    const float* b   = (const float*)d_in[4];
    const float* Wf  = (const float*)d_in[5];
    const float* bfv = (const float*)d_in[6];
    float* out = (float*)d_out;

    hipLaunchKernelGGL(k_fused, dim3(GRID), dim3(BLK), 0, stream,
                       x, ei, W0, W1, b, Wf, bfv, out);
}

// Round 3
// 286.593 us; speedup vs baseline: 1.3902x; 1.3902x over previous
//
#include <hip/hip_runtime.h>

#define N_NODES 2048
#define F_IN    2048
#define G1      10
#define NCLS    10
#define NEDGE   65536
#define JC      32          // split-K chunks over F_IN
#define JPER    64          // K elems per chunk
#define ROWS    128         // rows per GEMM block tile
#define GRID    512         // 2 blocks/CU x 256 CU -> co-residency proven in round 2
#define BLK     256

// Accumulators: zeroed at the END of each call by the epilogue (bss starts
// zero at module load), so atomics can begin immediately at the next call.
__device__ float g_y[N_NODES * 20];     // [row][k]: k<10 x@W0, k>=10 x@W1
__device__ float g_z[N_NODES * G1];     // scatter accumulator (Tx1@W1)
__device__ int   g_deg[N_NODES];        // degree histogram

// Multi-flag grid barrier (monotonic generations, no reset needed).
__device__ unsigned g_arrive[GRID];     // per-block arrival generation
__device__ unsigned g_bar_gen = 0;      // release generation

__device__ __forceinline__ void grid_barrier(unsigned target) {
    __syncthreads();
    if (blockIdx.x == 0) {
        if (threadIdx.x == 0) {
            __threadfence();
            __hip_atomic_store(&g_arrive[0], target, __ATOMIC_RELEASE,
                               __HIP_MEMORY_SCOPE_AGENT);
        }
        // 256 threads poll 2 flags each — no single-line contention.
        for (;;) {
            unsigned a = __hip_atomic_load(&g_arrive[threadIdx.x],
                                           __ATOMIC_ACQUIRE, __HIP_MEMORY_SCOPE_AGENT);
            unsigned b = __hip_atomic_load(&g_arrive[threadIdx.x + 256],
                                           __ATOMIC_ACQUIRE, __HIP_MEMORY_SCOPE_AGENT);
            if (__syncthreads_and((int)(a >= target && b >= target))) break;
            __builtin_amdgcn_s_sleep(1);
        }
        if (threadIdx.x == 0)
            __hip_atomic_store(&g_bar_gen, target, __ATOMIC_RELEASE,
                               __HIP_MEMORY_SCOPE_AGENT);
        __syncthreads();
    } else {
        if (threadIdx.x == 0) {
            __threadfence();
            __hip_atomic_store(&g_arrive[blockIdx.x], target, __ATOMIC_RELEASE,
                               __HIP_MEMORY_SCOPE_AGENT);
            while (__hip_atomic_load(&g_bar_gen, __ATOMIC_ACQUIRE,
                                     __HIP_MEMORY_SCOPE_AGENT) < target)
                __builtin_amdgcn_s_sleep(8);   // ~0.2 us poll granularity
        }
        __syncthreads();
    }
}

__global__ __launch_bounds__(256, 2) void k_fused(const float* __restrict__ x,
                                                  const int* __restrict__ ei,
                                                  const float* __restrict__ W0,
                                                  const float* __restrict__ W1,
                                                  const float* __restrict__ b,
                                                  const float* __restrict__ Wf,
                                                  const float* __restrict__ bfv,
                                                  float* __restrict__ out) {
    __shared__ __align__(16) float smem[ROWS * 65];   // 33.3 KB, stride 65
    const int tid = threadIdx.x;
    const int bx  = blockIdx.x;

    // Base generation: read before this block's first arrival -> uniform
    // across blocks (gen can't advance until ALL blocks arrive at barrier 1).
    unsigned base = __hip_atomic_load(&g_bar_gen, __ATOMIC_RELAXED,
                                      __HIP_MEMORY_SCOPE_AGENT);

    // ---- Phase 1: split-K GEMM x@[W0|W1] -> atomic g_y ; degree histogram ----
    {
        int jc   = bx & (JC - 1);          // 0..31
        int rb   = bx >> 5;                // 0..15
        int j0   = jc * JPER;
        int row0 = rb * ROWS;
        // stage 128x64 x-tile (LDS stride 65: conflict-free both sides)
        #pragma unroll
        for (int rep = 0; rep < 8; ++rep) {
            int idx = rep * 256 + tid;
            int r = idx >> 4, c4 = idx & 15;
            float4 v = *(const float4*)(x + (size_t)(row0 + r) * F_IN + j0 + c4 * 4);
            float* d = smem + r * 65 + c4 * 4;
            d[0] = v.x; d[1] = v.y; d[2] = v.z; d[3] = v.w;
        }
        // fused degree histogram: 128 edges per block (g_deg pre-zeroed)
        if (tid < 128) atomicAdd(&g_deg[ei[bx * 128 + tid]], 1);
        __syncthreads();

        int ri = tid & (ROWS - 1);         // row within tile
        int kg = tid >> 7;                 // wave-uniform: 0 -> W0, 1 -> W1
        const float* Wm = kg ? W1 : W0;
        float acc[G1];
        #pragma unroll
        for (int k = 0; k < G1; ++k) acc[k] = 0.f;
        const float* xr = smem + ri * 65;
        #pragma unroll
        for (int j = 0; j < JPER; ++j) {
            float xu = xr[j];
            const float* wr = Wm + (size_t)(j0 + j) * G1;   // uniform -> s_load
            #pragma unroll
            for (int k = 0; k < G1; ++k) acc[k] += xu * wr[k];
        }
        int row = row0 + ri;
        #pragma unroll
        for (int k = 0; k < G1; ++k)
            atomicAdd(&g_y[row * 20 + kg * 10 + k], acc[k]);   // g_y pre-zeroed
    }
    grid_barrier(base + 1);

    // ---- Phase 2: edge scatter, direct atomics into g_z (pre-zeroed) ----
    {
        int t = bx * 256 + tid;            // 131072 threads, 2 per edge
        int e = t >> 1, half = t & 1;
        int r = ei[e], c = ei[NEDGE + e];
        int dr = g_deg[r], dc = g_deg[c];
        float w = -(dr > 0 ? rsqrtf((float)dr) : 0.f) *
                   (dc > 0 ? rsqrtf((float)dc) : 0.f);
        const float* y1 = g_y + r * 20 + 10 + half * 5;
        float* dst = g_z + c * 10 + half * 5;
        #pragma unroll
        for (int kk = 0; kk < 5; ++kk) atomicAdd(&dst[kk], w * y1[kk]);
    }
    grid_barrier(base + 2);

    // ---- Phase 3: epilogue (blocks 0..7) + re-zero accumulators ----
    if (bx < 8) {
        int i = bx * 256 + tid;            // 0..2047
        float h[G1];
        #pragma unroll
        for (int k = 0; k < G1; ++k)
            h[k] = fmaxf(g_y[i * 20 + k] + g_z[i * 10 + k] + b[k], 0.f);
        float lo[NCLS];
        #pragma unroll
        for (int c = 0; c < NCLS; ++c) lo[c] = bfv[c];
        #pragma unroll
        for (int k = 0; k < G1; ++k) {
            float hk = h[k];
            #pragma unroll
            for (int c = 0; c < NCLS; ++c) lo[c] += hk * Wf[k * NCLS + c];
        }
        float m = lo[0];
        #pragma unroll
        for (int c = 1; c < NCLS; ++c) m = fmaxf(m, lo[c]);
        float s = 0.f;
        #pragma unroll
        for (int c = 0; c < NCLS; ++c) s += expf(lo[c] - m);
        float ls = logf(s);
        #pragma unroll
        for (int c = 0; c < NCLS; ++c) out[i * NCLS + c] = lo[c] - m - ls;
        // zero own slices for the next call (visible via kernel-boundary flush)
        #pragma unroll
        for (int k = 0; k < 20; ++k) g_y[i * 20 + k] = 0.f;
        #pragma unroll
        for (int k = 0; k < G1; ++k) g_z[i * 10 + k] = 0.f;
    } else if (bx == 8) {
        #pragma unroll
        for (int t = tid; t < N_NODES; t += 256) g_deg[t] = 0;
    }
}

extern "C" void kernel_launch(void* const* d_in, const int* in_sizes, int n_in,
                              void* d_out, int out_size, void* d_ws, size_t ws_size,
                              hipStream_t stream) {
    const float* x   = (const float*)d_in[0];
    const int*   ei  = (const int*)d_in[1];
    const float* W0  = (const float*)d_in[2];
    const float* W1  = (const float*)d_in[3];
    const float* b   = (const float*)d_in[4];
    const float* Wf  = (const float*)d_in[5];
    const float* bfv = (const float*)d_in[6];
    float* out = (float*)d_out;

    hipLaunchKernelGGL(k_fused, dim3(GRID), dim3(BLK), 0, stream,
                       x, ei, W0, W1, b, Wf, bfv, out);
}

// Round 4
// 189.713 us; speedup vs baseline: 2.1001x; 1.5107x over previous
//
#include <hip/hip_runtime.h>

#define N_NODES 2048
#define F_IN    2048
#define G1      10
#define NCLS    10
#define NEDGE   65536
#define JC      32          // split-K chunks over F_IN
#define JPER    64          // K elems per chunk
#define ROWS    128         // rows per GEMM block tile
#define GRID    512         // 2 blocks/CU x 256 CU -> co-residency proven (r2/r3)
#define BLK     256

// Accumulators: produced ONLY by device-scope atomics (coherence-point
// execution, never dirty in a local L2); zeroed at end of call for the next
// call (bss starts zero at module load).
__device__ float g_y[N_NODES * 20];     // [row][k]: k<10 x@W0, k>=10 x@W1
__device__ float g_z[N_NODES * G1];     // scatter accumulator (Tx1@W1)
__device__ int   g_deg[N_NODES];        // degree histogram

// Barrier flags — accessed ONLY via atomic RMWs (guaranteed coherent; no
// reliance on relaxed-load codegen, no acquire/release L2 inv/wb storms).
__device__ unsigned g_arrive[GRID];     // per-block generation (monotonic)
__device__ unsigned g_rel[64 * 16];     // 64 line-separated release slots

__device__ __forceinline__ unsigned coh_read(unsigned* p) {
    return __hip_atomic_fetch_add(p, 0u, __ATOMIC_RELAXED, __HIP_MEMORY_SCOPE_AGENT);
}
__device__ __forceinline__ void coh_write(unsigned* p, unsigned v) {
    (void)__hip_atomic_exchange(p, v, __ATOMIC_RELAXED, __HIP_MEMORY_SCOPE_AGENT);
}

// Arrive: EVERY wave drains its vmem (atomics reach coherence point), then
// thread 0 publishes the generation into this block's own slot.
__device__ __forceinline__ void bar_arrive(unsigned target) {
    asm volatile("s_waitcnt vmcnt(0)" ::: "memory");
    __syncthreads();
    if (threadIdx.x == 0) coh_write(&g_arrive[blockIdx.x], target);
}
// Block 0: wait for all 512 arrivals (256 threads x 2 slots), broadcast release.
__device__ __forceinline__ void bar_master_release(unsigned target) {
    for (;;) {
        unsigned a = coh_read(&g_arrive[threadIdx.x]);
        unsigned b = coh_read(&g_arrive[threadIdx.x + 256]);
        if (__syncthreads_and((int)(a >= target && b >= target))) break;
        __builtin_amdgcn_s_sleep(2);
    }
    if (threadIdx.x < 64) coh_write(&g_rel[threadIdx.x * 16], target);
    __syncthreads();
    asm volatile("" ::: "memory");   // keep later loads below the barrier
}
// Others: poll own line-separated release slot (~8 blocks/slot).
__device__ __forceinline__ void bar_wait(unsigned target) {
    if (threadIdx.x == 0) {
        unsigned* slot = &g_rel[(blockIdx.x & 63) * 16];
        while (coh_read(slot) < target) __builtin_amdgcn_s_sleep(8);
    }
    __syncthreads();
    asm volatile("" ::: "memory");
}

__global__ __launch_bounds__(256, 2) void k_fused(const float* __restrict__ x,
                                                  const int* __restrict__ ei,
                                                  const float* __restrict__ W0,
                                                  const float* __restrict__ W1,
                                                  const float* __restrict__ b,
                                                  const float* __restrict__ Wf,
                                                  const float* __restrict__ bfv,
                                                  float* __restrict__ out) {
    __shared__ __align__(16) float smem[ROWS * 65];   // 33.3 KB, stride 65
    const int tid = threadIdx.x;
    const int bx  = blockIdx.x;

    // Base generation: each block reads its OWN slot (value left by the
    // previous call's final arrival; 0 on first call). Uniform across blocks.
    unsigned base = coh_read(&g_arrive[bx]);

    // ---- Phase 1: split-K GEMM x@[W0|W1] -> atomic g_y ; degree histogram ----
    {
        int jc   = bx & (JC - 1);          // 0..31
        int rb   = bx >> 5;                // 0..15
        int j0   = jc * JPER;
        int row0 = rb * ROWS;
        #pragma unroll
        for (int rep = 0; rep < 8; ++rep) {
            int idx = rep * 256 + tid;
            int r = idx >> 4, c4 = idx & 15;
            float4 v = *(const float4*)(x + (size_t)(row0 + r) * F_IN + j0 + c4 * 4);
            float* d = smem + r * 65 + c4 * 4;
            d[0] = v.x; d[1] = v.y; d[2] = v.z; d[3] = v.w;
        }
        // fused degree histogram: 128 edges per block (g_deg pre-zeroed)
        if (tid < 128) atomicAdd(&g_deg[ei[bx * 128 + tid]], 1);
        __syncthreads();

        int ri = tid & (ROWS - 1);         // row within tile
        int kg = tid >> 7;                 // wave-uniform: 0 -> W0, 1 -> W1
        const float* Wm = kg ? W1 : W0;
        float acc[G1];
        #pragma unroll
        for (int k = 0; k < G1; ++k) acc[k] = 0.f;
        const float* xr = smem + ri * 65;
        #pragma unroll
        for (int j = 0; j < JPER; ++j) {
            float xu = xr[j];
            const float* wr = Wm + (size_t)(j0 + j) * G1;   // uniform -> s_load
            #pragma unroll
            for (int k = 0; k < G1; ++k) acc[k] += xu * wr[k];
        }
        int row = row0 + ri;
        #pragma unroll
        for (int k = 0; k < G1; ++k)
            atomicAdd(&g_y[row * 20 + kg * 10 + k], acc[k]);   // g_y pre-zeroed
    }
    bar_arrive(base + 1);
    if (bx == 0) bar_master_release(base + 1); else bar_wait(base + 1);

    // ---- Phase 2: edge scatter, direct atomics into g_z (pre-zeroed) ----
    {
        int t = bx * 256 + tid;            // 131072 threads, 2 per edge
        int e = t >> 1, half = t & 1;
        int r = ei[e], c = ei[NEDGE + e];
        int dr = g_deg[r], dc = g_deg[c];
        float w = -(dr > 0 ? rsqrtf((float)dr) : 0.f) *
                   (dc > 0 ? rsqrtf((float)dc) : 0.f);
        const float* y1 = g_y + r * 20 + 10 + half * 5;
        float* dst = g_z + c * 10 + half * 5;
        #pragma unroll
        for (int kk = 0; kk < 5; ++kk) atomicAdd(&dst[kk], w * y1[kk]);
    }
    bar_arrive(base + 2);
    if (bx > 8) return;                    // only blocks 0..8 run the epilogue
    if (bx == 0) bar_master_release(base + 2); else bar_wait(base + 2);

    // ---- Phase 3: epilogue (blocks 0..7) + re-zero accumulators (block 8) ----
    if (bx < 8) {
        int i = bx * 256 + tid;            // 0..2047
        float h[G1];
        #pragma unroll
        for (int k = 0; k < G1; ++k)
            h[k] = fmaxf(g_y[i * 20 + k] + g_z[i * 10 + k] + b[k], 0.f);
        float lo[NCLS];
        #pragma unroll
        for (int c = 0; c < NCLS; ++c) lo[c] = bfv[c];
        #pragma unroll
        for (int k = 0; k < G1; ++k) {
            float hk = h[k];
            #pragma unroll
            for (int c = 0; c < NCLS; ++c) lo[c] += hk * Wf[k * NCLS + c];
        }
        float m = lo[0];
        #pragma unroll
        for (int c = 1; c < NCLS; ++c) m = fmaxf(m, lo[c]);
        float s = 0.f;
        #pragma unroll
        for (int c = 0; c < NCLS; ++c) s += expf(lo[c] - m);
        float ls = logf(s);
        #pragma unroll
        for (int c = 0; c < NCLS; ++c) out[i * NCLS + c] = lo[c] - m - ls;
        // zero own rows for the next call (kernel-end writeback publishes)
        #pragma unroll
        for (int k = 0; k < 20; ++k) g_y[i * 20 + k] = 0.f;
        #pragma unroll
        for (int k = 0; k < G1; ++k) g_z[i * 10 + k] = 0.f;
    } else {                               // bx == 8
        #pragma unroll
        for (int t = tid; t < N_NODES; t += 256) g_deg[t] = 0;
    }
}

extern "C" void kernel_launch(void* const* d_in, const int* in_sizes, int n_in,
                              void* d_out, int out_size, void* d_ws, size_t ws_size,
                              hipStream_t stream) {
    const float* x   = (const float*)d_in[0];
    const int*   ei  = (const int*)d_in[1];
    const float* W0  = (const float*)d_in[2];
    const float* W1  = (const float*)d_in[3];
    const float* b   = (const float*)d_in[4];
    const float* Wf  = (const float*)d_in[5];
    const float* bfv = (const float*)d_in[6];
    float* out = (float*)d_out;

    hipLaunchKernelGGL(k_fused, dim3(GRID), dim3(BLK), 0, stream,
                       x, ei, W0, W1, b, Wf, bfv, out);
}

// Round 5
// 110.793 us; speedup vs baseline: 3.5961x; 1.7123x over previous
//
#include <hip/hip_runtime.h>

#define N_NODES 2048
#define F_IN    2048
#define G1      10
#define NCLS    10
#define NEDGE   65536
#define JC      32          // split-K chunks over F_IN
#define JPER    64          // K elems per chunk
#define ROWS    128         // rows per GEMM block tile
#define HS      128         // histogram slices (512 edges each)
#define ZS      64          // scatter slices per k-half

// Device intermediates — every element fully overwritten each call, no
// cross-call state, no pre-zeroing needed. Plain loads/stores only; kernel
// boundaries provide grid-wide sync + XCD coherence (the ~2-3 us native
// barrier; in-kernel SW barriers measured 55-85 us on this 8-XCD part).
__device__ float g_p[JC * 20 * N_NODES];        // split-K partials (5.25 MB)
__device__ int   g_degp[HS * N_NODES];          // degree hist partials (1 MB)
__device__ float g_y[N_NODES * 20];             // [row][k]: k<10 x@W0, k>=10 x@W1
__device__ float g_dis[N_NODES];                // deg>0 ? rsqrt(deg) : 0
__device__ float g_zp[2 * ZS * N_NODES * 5];    // scatter partials (5.25 MB)

// ---- K1: split-K GEMM x@[W0|W1] -> g_p ; fused LDS degree histogram ----
__global__ __launch_bounds__(256) void k_gemm(const float* __restrict__ x,
                                              const float* __restrict__ W0,
                                              const float* __restrict__ W1,
                                              const int* __restrict__ ei) {
    __shared__ __align__(16) float smem[ROWS * 65];   // 33.3 KB, stride 65
    const int tid = threadIdx.x;
    const int bx  = blockIdx.x;
    int jc   = bx & (JC - 1);          // 0..31
    int rb   = bx >> 5;                // 0..15
    int j0   = jc * JPER;
    int row0 = rb * ROWS;

    #pragma unroll
    for (int rep = 0; rep < 8; ++rep) {
        int idx = rep * 256 + tid;
        int r = idx >> 4, c4 = idx & 15;
        float4 v = *(const float4*)(x + (size_t)(row0 + r) * F_IN + j0 + c4 * 4);
        float* d = smem + r * 65 + c4 * 4;
        d[0] = v.x; d[1] = v.y; d[2] = v.z; d[3] = v.w;
    }
    __syncthreads();

    int ri = tid & (ROWS - 1);         // row within tile
    int kg = tid >> 7;                 // wave-uniform: 0 -> W0, 1 -> W1
    const float* Wm = kg ? W1 : W0;
    float acc[G1];
    #pragma unroll
    for (int k = 0; k < G1; ++k) acc[k] = 0.f;
    const float* xr = smem + ri * 65;
    #pragma unroll
    for (int j = 0; j < JPER; ++j) {
        float xu = xr[j];
        const float* wr = Wm + (size_t)(j0 + j) * G1;   // uniform -> s_load
        #pragma unroll
        for (int k = 0; k < G1; ++k) acc[k] += xu * wr[k];
    }
    int row = row0 + ri;
    #pragma unroll
    for (int k = 0; k < G1; ++k)
        g_p[((size_t)jc * 20 + kg * 10 + k) * N_NODES + row] = acc[k];  // coalesced

    // fused histogram: blocks 0..127 each own one 512-edge slice; reuse LDS
    // as int scratch (LDS atomics only — no fabric atomics anywhere).
    if (bx < HS) {
        __syncthreads();
        int* h = (int*)smem;
        #pragma unroll
        for (int t = tid; t < N_NODES; t += 256) h[t] = 0;
        __syncthreads();
        int base = bx * (NEDGE / HS);   // 512 edges
        atomicAdd(&h[ei[base + tid]], 1);
        atomicAdd(&h[ei[base + 256 + tid]], 1);
        __syncthreads();
        #pragma unroll
        for (int t = tid; t < N_NODES; t += 256)
            g_degp[bx * N_NODES + t] = h[t];
    }
}

// ---- K2: reduce GEMM partials -> g_y ; degree partials -> g_dis ----
__global__ __launch_bounds__(256) void k_reduce() {
    int t   = blockIdx.x * 256 + threadIdx.x;   // 160 blocks -> t < 40960
    int k   = t >> 11;
    int row = t & (N_NODES - 1);
    float s = 0.f;
    #pragma unroll 8
    for (int jc = 0; jc < JC; ++jc)
        s += g_p[((size_t)jc * 20 + k) * N_NODES + row];
    g_y[row * 20 + k] = s;
    if (t < N_NODES) {
        int d = 0;
        #pragma unroll 16
        for (int sl = 0; sl < HS; ++sl) d += g_degp[sl * N_NODES + t];
        g_dis[t] = (d > 0) ? rsqrtf((float)d) : 0.f;
    }
}

// ---- K3: edge scatter in projected space, LDS-privatized -> g_zp ----
__global__ __launch_bounds__(256) void k_scatter(const int* __restrict__ ei) {
    __shared__ float zl[N_NODES * 5];            // 40 KB
    int khalf  = blockIdx.x >> 6;
    int bslice = blockIdx.x & (ZS - 1);
    float4* zl4 = (float4*)zl;
    #pragma unroll
    for (int t = threadIdx.x; t < N_NODES * 5 / 4; t += 256)
        zl4[t] = make_float4(0.f, 0.f, 0.f, 0.f);
    __syncthreads();
    int base = bslice * (NEDGE / ZS);            // 1024 edges
    #pragma unroll
    for (int u = 0; u < NEDGE / ZS / 256; ++u) {
        int e = base + u * 256 + threadIdx.x;
        int r = ei[e], c = ei[NEDGE + e];
        float w = -g_dis[r] * g_dis[c];          // 0 if either deg==0
        const float* y1 = g_y + r * 20 + 10 + khalf * 5;
        float* zz = zl + c * 5;
        #pragma unroll
        for (int kk = 0; kk < 5; ++kk) atomicAdd(&zz[kk], w * y1[kk]);
    }
    __syncthreads();
    float4* dst = (float4*)(g_zp + ((size_t)khalf * ZS + bslice) * (N_NODES * 5));
    #pragma unroll
    for (int t = threadIdx.x; t < N_NODES * 5 / 4; t += 256) dst[t] = zl4[t];
}

// ---- K4: fused z-reduce + epilogue (relu(y0+z+b) @ Wf + log_softmax) ----
// 64 blocks x 320 threads: thread t handles (node i = t/10, channel k = t%10),
// reduces 64 z-partials, stages h in LDS; threads 0..31 finish one node each.
__global__ __launch_bounds__(320) void k_final(const float* __restrict__ b,
                                               const float* __restrict__ Wf,
                                               const float* __restrict__ bfv,
                                               float* __restrict__ out) {
    __shared__ float sh[320];
    int tid = threadIdx.x;
    int t = blockIdx.x * 320 + tid;              // t < 20480
    int i = t / 10, k = t - i * 10;
    int khalf = k / 5, kk = k - khalf * 5;
    float s = 0.f;
    #pragma unroll 16
    for (int sl = 0; sl < ZS; ++sl)
        s += g_zp[((size_t)khalf * ZS + sl) * (N_NODES * 5) + i * 5 + kk];
    sh[tid] = fmaxf(g_y[i * 20 + k] + s + b[k], 0.f);
    __syncthreads();
    if (tid < 32) {
        int node = blockIdx.x * 32 + tid;
        const float* h = sh + tid * 10;
        float lo[NCLS];
        #pragma unroll
        for (int c = 0; c < NCLS; ++c) lo[c] = bfv[c];
        #pragma unroll
        for (int kq = 0; kq < G1; ++kq) {
            float hk = h[kq];
            #pragma unroll
            for (int c = 0; c < NCLS; ++c) lo[c] += hk * Wf[kq * NCLS + c];
        }
        float m = lo[0];
        #pragma unroll
        for (int c = 1; c < NCLS; ++c) m = fmaxf(m, lo[c]);
        float sum = 0.f;
        #pragma unroll
        for (int c = 0; c < NCLS; ++c) sum += expf(lo[c] - m);
        float ls = logf(sum);
        #pragma unroll
        for (int c = 0; c < NCLS; ++c) out[node * NCLS + c] = lo[c] - m - ls;
    }
}

extern "C" void kernel_launch(void* const* d_in, const int* in_sizes, int n_in,
                              void* d_out, int out_size, void* d_ws, size_t ws_size,
                              hipStream_t stream) {
    const float* x   = (const float*)d_in[0];
    const int*   ei  = (const int*)d_in[1];
    const float* W0  = (const float*)d_in[2];
    const float* W1  = (const float*)d_in[3];
    const float* b   = (const float*)d_in[4];
    const float* Wf  = (const float*)d_in[5];
    const float* bfv = (const float*)d_in[6];
    float* out = (float*)d_out;

    k_gemm<<<dim3(JC * (N_NODES / ROWS)), 256, 0, stream>>>(x, W0, W1, ei);
    k_reduce<<<(N_NODES * 20) / 256, 256, 0, stream>>>();
    k_scatter<<<2 * ZS, 256, 0, stream>>>(ei);
    k_final<<<N_NODES / 32, 320, 0, stream>>>(b, Wf, bfv, out);
}